// Round 1
// baseline (1159.474 us; speedup 1.0000x reference)
//
#include <hip/hip_runtime.h>
#include <hip/hip_bf16.h>
#include <cstddef>

#define B_ 2
#define S_ 2048
#define E_ 1024
#define H_ 16
#define D_ 64
#define WIN_ 3

// ---------------------------------------------------------------------------
// Projection GEMM:  C[m,n] = sum_k X[m,k] * W[n,k] + bias[n]
// X: [B*S, E] row-major; W: [E_out, E_in] row-major (nn.Linear weight).
// Output written as [B, H, S, D]:  out[((b*H+h)*S + s)*D + d]
// Since BN == D == 64, each n-tile is exactly one head.
// ---------------------------------------------------------------------------
__global__ __launch_bounds__(256) void proj_kernel(
    const float* __restrict__ X,
    const float* __restrict__ Wq, const float* __restrict__ bq,
    const float* __restrict__ Wk, const float* __restrict__ bk,
    const float* __restrict__ Wv, const float* __restrict__ bv,
    float* __restrict__ qb, float* __restrict__ kb, float* __restrict__ vb)
{
    constexpr int BM = 64, BN = 64, BK = 16, LDT = 68; // LDT padded for bank conflicts, keeps 16B align
    const float* W; const float* bias; float* out;
    if (blockIdx.z == 0)      { W = Wq; bias = bq; out = qb; }
    else if (blockIdx.z == 1) { W = Wk; bias = bk; out = kb; }
    else                      { W = Wv; bias = bv; out = vb; }

    __shared__ float Xs[BK][LDT]; // K-major: Xs[kk][m]
    __shared__ float Ws[BK][LDT]; // K-major: Ws[kk][n]

    const int t  = threadIdx.x;
    const int m0 = blockIdx.x * BM;
    const int n0 = blockIdx.y * BN;
    const int tx = t & 15;       // n-group (4 cols)
    const int ty = t >> 4;       // m-group (4 rows)
    const int lr = t >> 2;       // 0..63 load row
    const int lc = (t & 3) * 4;  // 0,4,8,12 load col (k)

    const float* Xp = X + (size_t)(m0 + lr) * E_ + lc;
    const float* Wp = W + (size_t)(n0 + lr) * E_ + lc;

    float acc[4][4] = {};

    for (int k0 = 0; k0 < E_; k0 += BK) {
        float4 xv = *(const float4*)(Xp + k0);
        float4 wv = *(const float4*)(Wp + k0);
        __syncthreads();
        Xs[lc+0][lr] = xv.x; Xs[lc+1][lr] = xv.y; Xs[lc+2][lr] = xv.z; Xs[lc+3][lr] = xv.w;
        Ws[lc+0][lr] = wv.x; Ws[lc+1][lr] = wv.y; Ws[lc+2][lr] = wv.z; Ws[lc+3][lr] = wv.w;
        __syncthreads();
        #pragma unroll
        for (int kk = 0; kk < BK; ++kk) {
            float4 xa = *(const float4*)&Xs[kk][ty * 4];
            float4 wb = *(const float4*)&Ws[kk][tx * 4];
            float xr[4] = {xa.x, xa.y, xa.z, xa.w};
            float wr[4] = {wb.x, wb.y, wb.z, wb.w};
            #pragma unroll
            for (int i = 0; i < 4; ++i)
                #pragma unroll
                for (int j = 0; j < 4; ++j)
                    acc[i][j] += xr[i] * wr[j];
        }
    }

    const int h = n0 >> 6;                 // BN==D==64 -> one head per n-tile
    float4 bv4 = *(const float4*)(bias + n0 + tx * 4);
    #pragma unroll
    for (int i = 0; i < 4; ++i) {
        int m = m0 + ty * 4 + i;
        int b = m >> 11;                   // / S_ (2048)
        int s = m & (S_ - 1);
        float4 o;
        o.x = acc[i][0] + bv4.x;
        o.y = acc[i][1] + bv4.y;
        o.z = acc[i][2] + bv4.z;
        o.w = acc[i][3] + bv4.w;
        *(float4*)(out + (((size_t)(b * H_ + h) * S_) + s) * D_ + tx * 4) = o;
    }
}

// ---------------------------------------------------------------------------
// Attention: per (b,h), out[i] = sum_j p_ij v_j / sum_j p_ij
//   p_ij = exp(q_i.k_j / 8) for |i-j| > WIN, else 0   (inverted-window mask)
// No max-subtraction needed: logits are bounded (~±3) by construction.
// Block = 256 threads = 64 queries x 4 lanes; lane u owns dims [u*16, u*16+16)
// and (during scoring) keys j == u (mod 4).
// ---------------------------------------------------------------------------
__global__ __launch_bounds__(256) void attn_kernel(
    const float* __restrict__ Q, const float* __restrict__ K,
    const float* __restrict__ V, float* __restrict__ out)
{
    constexpr int TQ = 64, TK = 32, LDK = D_ + 4, LDP = TK + 4;
    __shared__ float Qs[TQ][LDK];   // ~17 KB
    __shared__ float Ks[TK][LDK];   // ~8.7 KB
    __shared__ float Vs[TK][LDK];   // ~8.7 KB
    __shared__ float Ps[TQ][LDP];   // ~9.2 KB

    const int t  = threadIdx.x;
    const int bh = blockIdx.y;
    const int q0 = blockIdx.x * TQ;

    const float* Qp = Q + ((size_t)bh * S_ + q0) * D_;
    const float* Kp = K + (size_t)bh * S_ * D_;
    const float* Vp = V + (size_t)bh * S_ * D_;

    // Load Q tile (4096 floats, 16 per thread)
    {
        int r = t >> 2;
        int c = (t & 3) * 16;
        #pragma unroll
        for (int i = 0; i < 4; ++i)
            *(float4*)&Qs[r][c + i * 4] = *(const float4*)(Qp + r * D_ + c + i * 4);
    }

    const int qi = t >> 2;  // query within tile
    const int u  = t & 3;   // sub-lane
    const int qg = q0 + qi; // global query index

    float acc[16] = {};
    float denom = 0.f;

    for (int k0 = 0; k0 < S_; k0 += TK) {
        __syncthreads();
        // Load K,V tiles (2048 floats each, 8 per thread per array)
        {
            int r = t >> 3;            // 0..31
            int c = (t & 7) * 8;       // 0..56
            const float* kr = Kp + (size_t)(k0 + r) * D_ + c;
            const float* vr = Vp + (size_t)(k0 + r) * D_ + c;
            float4 a0 = *(const float4*)(kr);
            float4 a1 = *(const float4*)(kr + 4);
            float4 b0 = *(const float4*)(vr);
            float4 b1 = *(const float4*)(vr + 4);
            *(float4*)&Ks[r][c]     = a0;
            *(float4*)&Ks[r][c + 4] = a1;
            *(float4*)&Vs[r][c]     = b0;
            *(float4*)&Vs[r][c + 4] = b1;
        }
        __syncthreads();

        // Scores for keys j = jj*4 + u
        float dot[8] = {};
        #pragma unroll
        for (int dc = 0; dc < D_; dc += 16) {
            float4 q4[4];
            #pragma unroll
            for (int i = 0; i < 4; ++i) q4[i] = *(const float4*)&Qs[qi][dc + i * 4];
            #pragma unroll
            for (int jj = 0; jj < 8; ++jj) {
                int j = jj * 4 + u;
                #pragma unroll
                for (int i = 0; i < 4; ++i) {
                    float4 k4 = *(const float4*)&Ks[j][dc + i * 4];
                    dot[jj] += q4[i].x * k4.x + q4[i].y * k4.y
                             + q4[i].z * k4.z + q4[i].w * k4.w;
                }
            }
        }
        #pragma unroll
        for (int jj = 0; jj < 8; ++jj) {
            int j  = jj * 4 + u;
            int kg = k0 + j;
            int dl = qg - kg; if (dl < 0) dl = -dl;
            float p = (dl <= WIN_) ? 0.f : __expf(dot[jj] * 0.125f);
            denom += p;
            Ps[qi][j] = p;
        }
        __syncthreads();  // Ps visible (cross-lane reads below)

        // PV: acc[c] += sum_j Ps[qi][j] * Vs[j][u*16 + c]
        #pragma unroll 4
        for (int j = 0; j < TK; ++j) {
            float p = Ps[qi][j];
            const float* vrow = &Vs[j][u * 16];
            #pragma unroll
            for (int c = 0; c < 16; c += 4) {
                float4 v4 = *(const float4*)(vrow + c);
                acc[c + 0] += p * v4.x;
                acc[c + 1] += p * v4.y;
                acc[c + 2] += p * v4.z;
                acc[c + 3] += p * v4.w;
            }
        }
    }

    // Reduce denom across the 4 lanes of this query group
    denom += __shfl_xor(denom, 1);
    denom += __shfl_xor(denom, 2);
    float inv = 1.f / denom;

    // Write out [B,S,H,D]: out[((b*S+s)*H + h)*D + d]
    int b = bh >> 4, h = bh & 15;
    float* op = out + (((size_t)b * S_ + qg) * H_ + h) * D_ + u * 16;
    #pragma unroll
    for (int c = 0; c < 16; c += 4) {
        float4 o;
        o.x = acc[c + 0] * inv;
        o.y = acc[c + 1] * inv;
        o.z = acc[c + 2] * inv;
        o.w = acc[c + 3] * inv;
        *(float4*)(op + c) = o;
    }
}

extern "C" void kernel_launch(void* const* d_in, const int* in_sizes, int n_in,
                              void* d_out, int out_size, void* d_ws, size_t ws_size,
                              hipStream_t stream) {
    const float* x  = (const float*)d_in[0];
    const float* Wq = (const float*)d_in[1];
    const float* bq = (const float*)d_in[2];
    const float* Wk = (const float*)d_in[3];
    const float* bk = (const float*)d_in[4];
    const float* Wv = (const float*)d_in[5];
    const float* bv = (const float*)d_in[6];
    float* out = (float*)d_out;

    const size_t per = (size_t)B_ * H_ * S_ * D_;  // 4,194,304 floats = 16 MB
    float* qb = (float*)d_ws;
    float* kb = qb + per;
    float* vb = kb + per;

    dim3 pgrid(B_ * S_ / 64, E_ / 64, 3);
    proj_kernel<<<pgrid, 256, 0, stream>>>(x, Wq, bq, Wk, bk, Wv, bv, qb, kb, vb);

    dim3 agrid(S_ / 64, B_ * H_);
    attn_kernel<<<agrid, 256, 0, stream>>>(qb, kb, vb, out);
}

// Round 2
// 484.189 us; speedup vs baseline: 2.3947x; 2.3947x over previous
//
#include <hip/hip_runtime.h>
#include <hip/hip_bf16.h>
#include <cstddef>
#include <cstdint>

#define B_ 2
#define S_ 2048
#define E_ 1024
#define H_ 16
#define D_ 64
#define WIN_ 3

using bf16x8 = __attribute__((ext_vector_type(8))) short;  // 8 bf16 = 4 VGPRs
using f32x4  = __attribute__((ext_vector_type(4))) float;  // MFMA C/D

static __device__ __forceinline__ unsigned short f2bf(float f) {
    union { float f; unsigned int u; } c; c.f = f;
    unsigned int r = c.u + 0x7FFF + ((c.u >> 16) & 1);   // round-to-nearest-even
    return (unsigned short)(r >> 16);
}

// ---------------------------------------------------------------------------
// Projection GEMM (fp32 mainloop):  C[m,n] = sum_k X[m,k] * W[n,k] + bias[n]
// z=0: Q -> bf16 [B,H,S,D], pre-scaled by 1/8
// z=1: K -> bf16 [B,H,S,D]
// z=2: V -> bf16 [B,H,D,S]  (transposed for PV B-operand staging)
// ---------------------------------------------------------------------------
__global__ __launch_bounds__(256) void proj_kernel(
    const float* __restrict__ X,
    const float* __restrict__ Wq, const float* __restrict__ bq,
    const float* __restrict__ Wk, const float* __restrict__ bk,
    const float* __restrict__ Wv, const float* __restrict__ bv,
    unsigned short* __restrict__ qb, unsigned short* __restrict__ kb,
    unsigned short* __restrict__ vb)
{
    constexpr int BM = 64, BN = 64, BK = 16, LDT = 68;
    const float* W; const float* bias; unsigned short* out;
    if (blockIdx.z == 0)      { W = Wq; bias = bq; out = qb; }
    else if (blockIdx.z == 1) { W = Wk; bias = bk; out = kb; }
    else                      { W = Wv; bias = bv; out = vb; }

    __shared__ float Xs[BK][LDT];
    __shared__ float Ws[BK][LDT];

    const int t  = threadIdx.x;
    const int m0 = blockIdx.x * BM;
    const int n0 = blockIdx.y * BN;
    const int tx = t & 15;
    const int ty = t >> 4;
    const int lr = t >> 2;
    const int lc = (t & 3) * 4;

    const float* Xp = X + (size_t)(m0 + lr) * E_ + lc;
    const float* Wp = W + (size_t)(n0 + lr) * E_ + lc;

    float acc[4][4] = {};

    for (int k0 = 0; k0 < E_; k0 += BK) {
        float4 xv = *(const float4*)(Xp + k0);
        float4 wv = *(const float4*)(Wp + k0);
        __syncthreads();
        Xs[lc+0][lr] = xv.x; Xs[lc+1][lr] = xv.y; Xs[lc+2][lr] = xv.z; Xs[lc+3][lr] = xv.w;
        Ws[lc+0][lr] = wv.x; Ws[lc+1][lr] = wv.y; Ws[lc+2][lr] = wv.z; Ws[lc+3][lr] = wv.w;
        __syncthreads();
        #pragma unroll
        for (int kk = 0; kk < BK; ++kk) {
            float4 xa = *(const float4*)&Xs[kk][ty * 4];
            float4 wb = *(const float4*)&Ws[kk][tx * 4];
            float xr[4] = {xa.x, xa.y, xa.z, xa.w};
            float wr[4] = {wb.x, wb.y, wb.z, wb.w};
            #pragma unroll
            for (int i = 0; i < 4; ++i)
                #pragma unroll
                for (int j = 0; j < 4; ++j)
                    acc[i][j] += xr[i] * wr[j];
        }
    }

    const int h  = n0 >> 6;              // BN==D==64: one head per n-tile
    const int b  = m0 >> 11;             // m0 is 64-aligned: same b for all 4 rows
    const int s0 = (m0 & (S_ - 1)) + ty * 4;
    float4 bv4 = *(const float4*)(bias + n0 + tx * 4);
    const float bj[4] = {bv4.x, bv4.y, bv4.z, bv4.w};

    if (blockIdx.z < 2) {
        const float sc = (blockIdx.z == 0) ? 0.125f : 1.0f;
        #pragma unroll
        for (int i = 0; i < 4; ++i) {
            ushort4 o;
            o.x = f2bf((acc[i][0] + bj[0]) * sc);
            o.y = f2bf((acc[i][1] + bj[1]) * sc);
            o.z = f2bf((acc[i][2] + bj[2]) * sc);
            o.w = f2bf((acc[i][3] + bj[3]) * sc);
            *(ushort4*)(out + (((size_t)(b * H_ + h) * S_) + s0 + i) * D_ + tx * 4) = o;
        }
    } else {
        #pragma unroll
        for (int j = 0; j < 4; ++j) {
            ushort4 o;
            o.x = f2bf(acc[0][j] + bj[j]);
            o.y = f2bf(acc[1][j] + bj[j]);
            o.z = f2bf(acc[2][j] + bj[j]);
            o.w = f2bf(acc[3][j] + bj[j]);
            *(ushort4*)(out + (((size_t)(b * H_ + h) * D_) + tx * 4 + j) * S_ + s0) = o;
        }
    }
}

// ---------------------------------------------------------------------------
// MFMA attention. Block = 256 threads = 4 waves; 128 queries/block, 32/wave.
// Per K-tile (64 keys): S = QK^T via mfma_f32_16x16x32_bf16, exp+invert-mask,
// P (bf16-truncated fp32) -> LDS (C-layout -> A-layout transpose), PV MFMA.
// No max-subtraction needed: logits bounded (~+-3) by construction.
// Denominator accumulated from the SAME truncated p values so the bf16
// truncation bias cancels exactly under normalization.
// ---------------------------------------------------------------------------
__global__ __launch_bounds__(256) void attn_kernel(
    const unsigned short* __restrict__ Q, const unsigned short* __restrict__ K,
    const unsigned short* __restrict__ V, float* __restrict__ out)
{
    constexpr int TQ = 128, TK = 64;
    constexpr int KSTR = 72;   // shorts per row (144 B, 16B-aligned, bank-balanced)
    constexpr int PSTR = 68;   // floats per row (272 B, 16B-aligned)

    __shared__ unsigned short Ks[TK * KSTR];   // 9216 B   [key][d]
    __shared__ unsigned short Vt[D_ * KSTR];   // 9216 B   [d][key]
    __shared__ float          Pq[TQ * PSTR];   // 34816 B  [q_loc][key]

    const int t    = threadIdx.x;
    const int lane = t & 63;
    const int w    = t >> 6;        // wave 0..3
    const int l15  = lane & 15;
    const int quad = lane >> 4;
    const int bh   = blockIdx.y;
    const int q0   = blockIdx.x * TQ;

    const unsigned short* Qp = Q + (size_t)bh * S_ * D_;
    const unsigned short* Kp = K + (size_t)bh * S_ * D_;
    const unsigned short* Vp = V + (size_t)bh * D_ * S_;   // [d][s]

    // Q A-frags (held in regs for the whole kernel): [mt][kstep]
    bf16x8 qf[2][2];
    #pragma unroll
    for (int mt = 0; mt < 2; ++mt)
        #pragma unroll
        for (int ks = 0; ks < 2; ++ks)
            qf[mt][ks] = *(const bf16x8*)(Qp + (size_t)(q0 + w*32 + mt*16 + l15) * D_
                                          + ks*32 + quad*8);

    f32x4 Oacc[2][4];
    #pragma unroll
    for (int mt = 0; mt < 2; ++mt)
        #pragma unroll
        for (int nt = 0; nt < 4; ++nt)
            #pragma unroll
            for (int r = 0; r < 4; ++r) Oacc[mt][nt][r] = 0.f;
    float dsum[2][4] = {};

    const int srow = t >> 2;          // 0..63
    const int scol = (t & 3) * 16;    // shorts

    for (int k0 = 0; k0 < S_; k0 += TK) {
        __syncthreads();   // protect Ks/Vt from overwrite while prior iter reads
        {
            const unsigned short* kg = Kp + (size_t)(k0 + srow) * D_ + scol;
            const unsigned short* vg = Vp + (size_t)srow * S_ + k0 + scol;
            uint4 ka = *(const uint4*)(kg);
            uint4 kb2 = *(const uint4*)(kg + 8);
            uint4 va = *(const uint4*)(vg);
            uint4 vb2 = *(const uint4*)(vg + 8);
            *(uint4*)&Ks[srow * KSTR + scol]     = ka;
            *(uint4*)&Ks[srow * KSTR + scol + 8] = kb2;
            *(uint4*)&Vt[srow * KSTR + scol]     = va;
            *(uint4*)&Vt[srow * KSTR + scol + 8] = vb2;
        }
        __syncthreads();

        // ---- S = Q K^T  (per wave: 32 q x 64 keys) ----
        f32x4 sacc[2][4];
        #pragma unroll
        for (int mt = 0; mt < 2; ++mt)
            #pragma unroll
            for (int nt = 0; nt < 4; ++nt)
                #pragma unroll
                for (int r = 0; r < 4; ++r) sacc[mt][nt][r] = 0.f;

        #pragma unroll
        for (int nt = 0; nt < 4; ++nt) {
            bf16x8 kf0 = *(const bf16x8*)&Ks[(nt*16 + l15) * KSTR + quad*8];
            bf16x8 kf1 = *(const bf16x8*)&Ks[(nt*16 + l15) * KSTR + 32 + quad*8];
            #pragma unroll
            for (int mt = 0; mt < 2; ++mt) {
                sacc[mt][nt] = __builtin_amdgcn_mfma_f32_16x16x32_bf16(
                    qf[mt][0], kf0, sacc[mt][nt], 0, 0, 0);
                sacc[mt][nt] = __builtin_amdgcn_mfma_f32_16x16x32_bf16(
                    qf[mt][1], kf1, sacc[mt][nt], 0, 0, 0);
            }
        }

        // ---- exp + inverted-window mask; truncate to bf16 grid; P -> LDS ----
        #pragma unroll
        for (int mt = 0; mt < 2; ++mt) {
            #pragma unroll
            for (int nt = 0; nt < 4; ++nt) {
                const int kg_ = k0 + nt*16 + l15;
                #pragma unroll
                for (int r = 0; r < 4; ++r) {
                    const int ql  = w*32 + mt*16 + quad*4 + r;
                    const int dlt = (q0 + ql) - kg_;
                    const bool masked = (dlt <= WIN_) && (dlt >= -WIN_);
                    float p = masked ? 0.f : __expf(sacc[mt][nt][r]);
                    union { float f; unsigned int u; } c; c.f = p;
                    c.u &= 0xFFFF0000u;            // bf16-representable (truncate)
                    dsum[mt][r] += c.f;
                    Pq[ql * PSTR + nt*16 + l15] = c.f;
                }
            }
        }
        __syncthreads();   // conservative: P visible before A-frag reads

        // ---- O += P V  ----
        #pragma unroll
        for (int ks = 0; ks < 2; ++ks) {
            bf16x8 pf[2];
            #pragma unroll
            for (int mt = 0; mt < 2; ++mt) {
                const float* pp = &Pq[(w*32 + mt*16 + l15) * PSTR + ks*32 + quad*8];
                f32x4 plo = *(const f32x4*)pp;
                f32x4 phi = *(const f32x4*)(pp + 4);
                union { unsigned int u[4]; bf16x8 v; } pk;
                union { float f; unsigned int u; } a0, a1;
                a0.f = plo[0]; a1.f = plo[1];
                pk.u[0] = __builtin_amdgcn_perm(a1.u, a0.u, 0x07060302u);
                a0.f = plo[2]; a1.f = plo[3];
                pk.u[1] = __builtin_amdgcn_perm(a1.u, a0.u, 0x07060302u);
                a0.f = phi[0]; a1.f = phi[1];
                pk.u[2] = __builtin_amdgcn_perm(a1.u, a0.u, 0x07060302u);
                a0.f = phi[2]; a1.f = phi[3];
                pk.u[3] = __builtin_amdgcn_perm(a1.u, a0.u, 0x07060302u);
                pf[mt] = pk.v;
            }
            #pragma unroll
            for (int nt = 0; nt < 4; ++nt) {
                bf16x8 vf = *(const bf16x8*)&Vt[(nt*16 + l15) * KSTR + ks*32 + quad*8];
                #pragma unroll
                for (int mt = 0; mt < 2; ++mt)
                    Oacc[mt][nt] = __builtin_amdgcn_mfma_f32_16x16x32_bf16(
                        pf[mt], vf, Oacc[mt][nt], 0, 0, 0);
            }
        }
    }

    // ---- normalize + store: out [B,S,H,D] fp32 ----
    const int b  = bh >> 4;
    const int hh = bh & 15;
    #pragma unroll
    for (int mt = 0; mt < 2; ++mt) {
        #pragma unroll
        for (int r = 0; r < 4; ++r) {
            float d = dsum[mt][r];
            d += __shfl_xor(d, 1);
            d += __shfl_xor(d, 2);
            d += __shfl_xor(d, 4);
            d += __shfl_xor(d, 8);
            const float iv = 1.f / d;
            const int qg = q0 + w*32 + mt*16 + quad*4 + r;
            float* op = out + (((size_t)b * S_ + qg) * H_ + hh) * D_;
            #pragma unroll
            for (int nt = 0; nt < 4; ++nt)
                op[nt*16 + l15] = Oacc[mt][nt][r] * iv;
        }
    }
}

extern "C" void kernel_launch(void* const* d_in, const int* in_sizes, int n_in,
                              void* d_out, int out_size, void* d_ws, size_t ws_size,
                              hipStream_t stream) {
    const float* x  = (const float*)d_in[0];
    const float* Wq = (const float*)d_in[1];
    const float* bq = (const float*)d_in[2];
    const float* Wk = (const float*)d_in[3];
    const float* bk = (const float*)d_in[4];
    const float* Wv = (const float*)d_in[5];
    const float* bv = (const float*)d_in[6];
    float* out = (float*)d_out;

    const size_t per = (size_t)B_ * H_ * S_ * D_;   // 4,194,304 elements
    unsigned short* qb = (unsigned short*)d_ws;
    unsigned short* kb = qb + per;
    unsigned short* vb = kb + per;

    dim3 pgrid(B_ * S_ / 64, E_ / 64, 3);
    proj_kernel<<<pgrid, 256, 0, stream>>>(x, Wq, bq, Wk, bk, Wv, bv, qb, kb, vb);

    dim3 agrid(S_ / 128, B_ * H_);
    attn_kernel<<<agrid, 256, 0, stream>>>(qb, kb, vb, out);
}

// Round 3
// 193.766 us; speedup vs baseline: 5.9839x; 2.4988x over previous
//
#include <hip/hip_runtime.h>
#include <hip/hip_bf16.h>
#include <cstddef>
#include <cstdint>

#define B_ 2
#define S_ 2048
#define E_ 1024
#define H_ 16
#define D_ 64
#define WIN_ 3

using bf16x8 = __attribute__((ext_vector_type(8))) short;  // 8 bf16 = 4 VGPRs
using f32x4  = __attribute__((ext_vector_type(4))) float;  // MFMA C/D

static __device__ __forceinline__ unsigned short f2bf(float f) {
    union { float f; unsigned int u; } c; c.f = f;
    unsigned int r = c.u + 0x7FFF + ((c.u >> 16) & 1);   // round-to-nearest-even
    return (unsigned short)(r >> 16);
}

static __device__ __forceinline__ void gload16(const void* g, void* l) {
    __builtin_amdgcn_global_load_lds(
        (const __attribute__((address_space(1))) void*)g,
        (__attribute__((address_space(3))) void*)l, 16, 0, 0);
}

// ---------------------------------------------------------------------------
// fp32 -> bf16 cast: y=0: x (4M elems), y=1..3: Wq/Wk/Wv (1M each)
// ---------------------------------------------------------------------------
__global__ __launch_bounds__(256) void cast_kernel(
    const float* __restrict__ X,  const float* __restrict__ Wq,
    const float* __restrict__ Wk, const float* __restrict__ Wv,
    unsigned short* __restrict__ xb,  unsigned short* __restrict__ wqb,
    unsigned short* __restrict__ wkb, unsigned short* __restrict__ wvb)
{
    const float* src; unsigned short* dst; int n;
    switch (blockIdx.y) {
        case 0:  src = X;  dst = xb;  n = B_ * S_ * E_; break;
        case 1:  src = Wq; dst = wqb; n = E_ * E_;      break;
        case 2:  src = Wk; dst = wkb; n = E_ * E_;      break;
        default: src = Wv; dst = wvb; n = E_ * E_;      break;
    }
    int i = (blockIdx.x * 256 + threadIdx.x) * 8;
    if (i >= n) return;
    float4 a = *(const float4*)(src + i);
    float4 b = *(const float4*)(src + i + 4);
    ushort4 lo, hi;
    lo.x = f2bf(a.x); lo.y = f2bf(a.y); lo.z = f2bf(a.z); lo.w = f2bf(a.w);
    hi.x = f2bf(b.x); hi.y = f2bf(b.y); hi.z = f2bf(b.z); hi.w = f2bf(b.w);
    *(ushort4*)(dst + i)     = lo;
    *(ushort4*)(dst + i + 4) = hi;
}

// ---------------------------------------------------------------------------
// bf16 MFMA projection GEMM (m97 structure): C[i,j] = sum_k A[i,k]*B[j,k]
// 128x128 tile, BK=64, 4 waves (2x2), 4x4 frags of 16x16x32, global_load_lds.
// z=0: A=x, B=Wq -> q bf16 [B,H,S,D] scaled 1/8
// z=1: A=x, B=Wk -> k bf16 [B,H,S,D]
// z=2: A=Wv, B=x (operands swapped!) -> v bf16 [B,H,D,S]; the C-layout's
//      l15 columns land along S so the transposed store is coalesced.
// ---------------------------------------------------------------------------
__global__ __launch_bounds__(256, 3) void gemm_kernel(
    const unsigned short* __restrict__ xb,
    const unsigned short* __restrict__ wqb, const unsigned short* __restrict__ wkb,
    const unsigned short* __restrict__ wvb,
    const float* __restrict__ bq, const float* __restrict__ bk,
    const float* __restrict__ bv,
    unsigned short* __restrict__ qb, unsigned short* __restrict__ kb,
    unsigned short* __restrict__ vb)
{
    constexpr int BM = 128, BK = 64;
    __shared__ unsigned short As[BM * BK];   // 16 KB, row-major [row][k], no pad
    __shared__ unsigned short Bs[BM * BK];   // 16 KB

    const int t    = threadIdx.x;
    const int lane = t & 63;
    const int w    = t >> 6;
    const int l15  = lane & 15;
    const int quad = lane >> 4;
    const int wm   = w & 1;
    const int wn   = w >> 1;
    const int m0   = blockIdx.x * BM;
    const int n0   = blockIdx.y * BM;
    const int z    = blockIdx.z;

    const unsigned short *Ab, *Bb; const float* bias; unsigned short* outp;
    int i0, j0; float sc = 1.0f;
    if (z == 0)      { Ab = xb;  Bb = wqb; bias = bq; outp = qb; i0 = m0; j0 = n0; sc = 0.125f; }
    else if (z == 1) { Ab = xb;  Bb = wkb; bias = bk; outp = kb; i0 = m0; j0 = n0; }
    else             { Ab = wvb; Bb = xb;  bias = bv; outp = vb; i0 = n0; j0 = m0; }

    const int lrow   = lane >> 3;        // 0..7
    const int lchunk = (lane & 7) * 8;   // element offset within row

    f32x4 acc[4][4];
    #pragma unroll
    for (int mt = 0; mt < 4; ++mt)
        #pragma unroll
        for (int nt = 0; nt < 4; ++nt)
            #pragma unroll
            for (int r = 0; r < 4; ++r) acc[mt][nt][r] = 0.f;

    for (int k0 = 0; k0 < E_; k0 += BK) {
        __syncthreads();
        #pragma unroll
        for (int is = 0; is < 4; ++is) {
            int r = (w * 4 + is) * 8 + lrow;
            gload16(Ab + (size_t)(i0 + r) * E_ + k0 + lchunk, &As[r * BK + lchunk]);
            gload16(Bb + (size_t)(j0 + r) * E_ + k0 + lchunk, &Bs[r * BK + lchunk]);
        }
        __syncthreads();

        #pragma unroll
        for (int ks = 0; ks < 2; ++ks) {
            bf16x8 af[4], bfr[4];
            #pragma unroll
            for (int mt = 0; mt < 4; ++mt)
                af[mt] = *(const bf16x8*)&As[(wm*64 + mt*16 + l15) * BK + ks*32 + quad*8];
            #pragma unroll
            for (int nt = 0; nt < 4; ++nt)
                bfr[nt] = *(const bf16x8*)&Bs[(wn*64 + nt*16 + l15) * BK + ks*32 + quad*8];
            #pragma unroll
            for (int mt = 0; mt < 4; ++mt)
                #pragma unroll
                for (int nt = 0; nt < 4; ++nt)
                    acc[mt][nt] = __builtin_amdgcn_mfma_f32_16x16x32_bf16(
                        af[mt], bfr[nt], acc[mt][nt], 0, 0, 0);
        }
    }

    if (z < 2) {
        float bj[4];
        #pragma unroll
        for (int nt = 0; nt < 4; ++nt) bj[nt] = bias[j0 + wn*64 + nt*16 + l15];
        #pragma unroll
        for (int mt = 0; mt < 4; ++mt) {
            #pragma unroll
            for (int r = 0; r < 4; ++r) {
                int i = i0 + wm*64 + mt*16 + quad*4 + r;   // m index (b,s)
                int b = i >> 11, s = i & (S_ - 1);
                #pragma unroll
                for (int nt = 0; nt < 4; ++nt) {
                    int j = j0 + wn*64 + nt*16 + l15;      // n index (h,d)
                    int h = j >> 6, d = j & 63;
                    outp[(((size_t)(b * H_ + h) * S_) + s) * D_ + d] =
                        f2bf((acc[mt][nt][r] + bj[nt]) * sc);
                }
            }
        }
    } else {
        #pragma unroll
        for (int mt = 0; mt < 4; ++mt) {
            #pragma unroll
            for (int r = 0; r < 4; ++r) {
                int i = i0 + wm*64 + mt*16 + quad*4 + r;   // n index (h,d)
                int h = i >> 6, d = i & 63;
                float bi = bias[i];
                #pragma unroll
                for (int nt = 0; nt < 4; ++nt) {
                    int j = j0 + wn*64 + nt*16 + l15;      // m index (b,s)
                    int b = j >> 11, s = j & (S_ - 1);
                    outp[(((size_t)(b * H_ + h) * D_) + d) * S_ + s] =
                        f2bf(acc[mt][nt][r] + bi);
                }
            }
        }
    }
}

// ---------------------------------------------------------------------------
// MFMA attention (unchanged from R1). Block = 4 waves; 128 queries, TK=64.
// ---------------------------------------------------------------------------
__global__ __launch_bounds__(256) void attn_kernel(
    const unsigned short* __restrict__ Q, const unsigned short* __restrict__ K,
    const unsigned short* __restrict__ V, float* __restrict__ out)
{
    constexpr int TQ = 128, TK = 64;
    constexpr int KSTR = 72;
    constexpr int PSTR = 68;

    __shared__ unsigned short Ks[TK * KSTR];
    __shared__ unsigned short Vt[D_ * KSTR];
    __shared__ float          Pq[TQ * PSTR];

    const int t    = threadIdx.x;
    const int lane = t & 63;
    const int w    = t >> 6;
    const int l15  = lane & 15;
    const int quad = lane >> 4;
    const int bh   = blockIdx.y;
    const int q0   = blockIdx.x * TQ;

    const unsigned short* Qp = Q + (size_t)bh * S_ * D_;
    const unsigned short* Kp = K + (size_t)bh * S_ * D_;
    const unsigned short* Vp = V + (size_t)bh * D_ * S_;

    bf16x8 qf[2][2];
    #pragma unroll
    for (int mt = 0; mt < 2; ++mt)
        #pragma unroll
        for (int ks = 0; ks < 2; ++ks)
            qf[mt][ks] = *(const bf16x8*)(Qp + (size_t)(q0 + w*32 + mt*16 + l15) * D_
                                          + ks*32 + quad*8);

    f32x4 Oacc[2][4];
    #pragma unroll
    for (int mt = 0; mt < 2; ++mt)
        #pragma unroll
        for (int nt = 0; nt < 4; ++nt)
            #pragma unroll
            for (int r = 0; r < 4; ++r) Oacc[mt][nt][r] = 0.f;
    float dsum[2][4] = {};

    const int srow = t >> 2;
    const int scol = (t & 3) * 16;

    for (int k0 = 0; k0 < S_; k0 += TK) {
        __syncthreads();
        {
            const unsigned short* kg = Kp + (size_t)(k0 + srow) * D_ + scol;
            const unsigned short* vg = Vp + (size_t)srow * S_ + k0 + scol;
            uint4 ka = *(const uint4*)(kg);
            uint4 kb2 = *(const uint4*)(kg + 8);
            uint4 va = *(const uint4*)(vg);
            uint4 vb2 = *(const uint4*)(vg + 8);
            *(uint4*)&Ks[srow * KSTR + scol]     = ka;
            *(uint4*)&Ks[srow * KSTR + scol + 8] = kb2;
            *(uint4*)&Vt[srow * KSTR + scol]     = va;
            *(uint4*)&Vt[srow * KSTR + scol + 8] = vb2;
        }
        __syncthreads();

        f32x4 sacc[2][4];
        #pragma unroll
        for (int mt = 0; mt < 2; ++mt)
            #pragma unroll
            for (int nt = 0; nt < 4; ++nt)
                #pragma unroll
                for (int r = 0; r < 4; ++r) sacc[mt][nt][r] = 0.f;

        #pragma unroll
        for (int nt = 0; nt < 4; ++nt) {
            bf16x8 kf0 = *(const bf16x8*)&Ks[(nt*16 + l15) * KSTR + quad*8];
            bf16x8 kf1 = *(const bf16x8*)&Ks[(nt*16 + l15) * KSTR + 32 + quad*8];
            #pragma unroll
            for (int mt = 0; mt < 2; ++mt) {
                sacc[mt][nt] = __builtin_amdgcn_mfma_f32_16x16x32_bf16(
                    qf[mt][0], kf0, sacc[mt][nt], 0, 0, 0);
                sacc[mt][nt] = __builtin_amdgcn_mfma_f32_16x16x32_bf16(
                    qf[mt][1], kf1, sacc[mt][nt], 0, 0, 0);
            }
        }

        #pragma unroll
        for (int mt = 0; mt < 2; ++mt) {
            #pragma unroll
            for (int nt = 0; nt < 4; ++nt) {
                const int kg_ = k0 + nt*16 + l15;
                #pragma unroll
                for (int r = 0; r < 4; ++r) {
                    const int ql  = w*32 + mt*16 + quad*4 + r;
                    const int dlt = (q0 + ql) - kg_;
                    const bool masked = (dlt <= WIN_) && (dlt >= -WIN_);
                    float p = masked ? 0.f : __expf(sacc[mt][nt][r]);
                    union { float f; unsigned int u; } c; c.f = p;
                    c.u &= 0xFFFF0000u;
                    dsum[mt][r] += c.f;
                    Pq[ql * PSTR + nt*16 + l15] = c.f;
                }
            }
        }
        __syncthreads();

        #pragma unroll
        for (int ks = 0; ks < 2; ++ks) {
            bf16x8 pf[2];
            #pragma unroll
            for (int mt = 0; mt < 2; ++mt) {
                const float* pp = &Pq[(w*32 + mt*16 + l15) * PSTR + ks*32 + quad*8];
                f32x4 plo = *(const f32x4*)pp;
                f32x4 phi = *(const f32x4*)(pp + 4);
                union { unsigned int u[4]; bf16x8 v; } pk;
                union { float f; unsigned int u; } a0, a1;
                a0.f = plo[0]; a1.f = plo[1];
                pk.u[0] = __builtin_amdgcn_perm(a1.u, a0.u, 0x07060302u);
                a0.f = plo[2]; a1.f = plo[3];
                pk.u[1] = __builtin_amdgcn_perm(a1.u, a0.u, 0x07060302u);
                a0.f = phi[0]; a1.f = phi[1];
                pk.u[2] = __builtin_amdgcn_perm(a1.u, a0.u, 0x07060302u);
                a0.f = phi[2]; a1.f = phi[3];
                pk.u[3] = __builtin_amdgcn_perm(a1.u, a0.u, 0x07060302u);
                pf[mt] = pk.v;
            }
            #pragma unroll
            for (int nt = 0; nt < 4; ++nt) {
                bf16x8 vf = *(const bf16x8*)&Vt[(nt*16 + l15) * KSTR + ks*32 + quad*8];
                #pragma unroll
                for (int mt = 0; mt < 2; ++mt)
                    Oacc[mt][nt] = __builtin_amdgcn_mfma_f32_16x16x32_bf16(
                        pf[mt], vf, Oacc[mt][nt], 0, 0, 0);
            }
        }
    }

    const int b  = bh >> 4;
    const int hh = bh & 15;
    #pragma unroll
    for (int mt = 0; mt < 2; ++mt) {
        #pragma unroll
        for (int r = 0; r < 4; ++r) {
            float d = dsum[mt][r];
            d += __shfl_xor(d, 1);
            d += __shfl_xor(d, 2);
            d += __shfl_xor(d, 4);
            d += __shfl_xor(d, 8);
            const float iv = 1.f / d;
            const int qg = q0 + w*32 + mt*16 + quad*4 + r;
            float* op = out + (((size_t)b * S_ + qg) * H_ + hh) * D_;
            #pragma unroll
            for (int nt = 0; nt < 4; ++nt)
                op[nt*16 + l15] = Oacc[mt][nt][r] * iv;
        }
    }
}

extern "C" void kernel_launch(void* const* d_in, const int* in_sizes, int n_in,
                              void* d_out, int out_size, void* d_ws, size_t ws_size,
                              hipStream_t stream) {
    const float* x  = (const float*)d_in[0];
    const float* Wq = (const float*)d_in[1];
    const float* bq = (const float*)d_in[2];
    const float* Wk = (const float*)d_in[3];
    const float* bk = (const float*)d_in[4];
    const float* Wv = (const float*)d_in[5];
    const float* bv = (const float*)d_in[6];
    float* out = (float*)d_out;

    const size_t per = (size_t)B_ * H_ * S_ * D_;   // 4,194,304 elements
    const size_t wsz = (size_t)E_ * E_;             // 1,048,576
    unsigned short* qb  = (unsigned short*)d_ws;
    unsigned short* kb  = qb + per;
    unsigned short* vb  = kb + per;
    unsigned short* xbf = vb + per;
    unsigned short* wqb = xbf + per;
    unsigned short* wkb = wqb + wsz;
    unsigned short* wvb = wkb + wsz;

    dim3 cgrid((B_ * S_ * E_ + 2047) / 2048, 4);
    cast_kernel<<<cgrid, 256, 0, stream>>>(x, Wq, Wk, Wv, xbf, wqb, wkb, wvb);

    dim3 ggrid(B_ * S_ / 128, E_ / 128, 3);
    gemm_kernel<<<ggrid, 256, 0, stream>>>(xbf, wqb, wkb, wvb, bq, bk, bv, qb, kb, vb);

    dim3 agrid(S_ / 128, B_ * H_);
    attn_kernel<<<agrid, 256, 0, stream>>>(qb, kb, vb, out);
}

// Round 4
// 175.384 us; speedup vs baseline: 6.6111x; 1.1048x over previous
//
#include <hip/hip_runtime.h>
#include <hip/hip_bf16.h>
#include <cstddef>
#include <cstdint>

#define B_ 2
#define S_ 2048
#define E_ 1024
#define H_ 16
#define D_ 64
#define WIN_ 3

using bf16x8 = __attribute__((ext_vector_type(8))) short;  // 8 bf16 = 4 VGPRs
using f32x4  = __attribute__((ext_vector_type(4))) float;  // MFMA C/D

static __device__ __forceinline__ unsigned short f2bf(float f) {
    union { float f; unsigned int u; } c; c.f = f;
    unsigned int r = c.u + 0x7FFF + ((c.u >> 16) & 1);   // round-to-nearest-even
    return (unsigned short)(r >> 16);
}

static __device__ __forceinline__ void gload16(const void* g, void* l) {
    __builtin_amdgcn_global_load_lds(
        (const __attribute__((address_space(1))) void*)g,
        (__attribute__((address_space(3))) void*)l, 16, 0, 0);
}

// XOR-swizzled LDS index (shorts) for [row][chunk-of-8-shorts] tiles with
// 64-short rows: slot = chunk ^ (row & 7). Breaks the 128B-row 16-way bank
// aliasing while staying global_load_lds-compatible (lane*16B contiguous).
#define SWZ(row, c) ((((row) * 8) + ((c) ^ ((row) & 7))) * 8)

// ---------------------------------------------------------------------------
// fp32 -> bf16 cast: y=0: x (4M elems), y=1..3: Wq/Wk/Wv (1M each)
// ---------------------------------------------------------------------------
__global__ __launch_bounds__(256) void cast_kernel(
    const float* __restrict__ X,  const float* __restrict__ Wq,
    const float* __restrict__ Wk, const float* __restrict__ Wv,
    unsigned short* __restrict__ xb,  unsigned short* __restrict__ wqb,
    unsigned short* __restrict__ wkb, unsigned short* __restrict__ wvb)
{
    const float* src; unsigned short* dst; int n;
    switch (blockIdx.y) {
        case 0:  src = X;  dst = xb;  n = B_ * S_ * E_; break;
        case 1:  src = Wq; dst = wqb; n = E_ * E_;      break;
        case 2:  src = Wk; dst = wkb; n = E_ * E_;      break;
        default: src = Wv; dst = wvb; n = E_ * E_;      break;
    }
    int i = (blockIdx.x * 256 + threadIdx.x) * 8;
    if (i >= n) return;
    float4 a = *(const float4*)(src + i);
    float4 b = *(const float4*)(src + i + 4);
    ushort4 lo, hi;
    lo.x = f2bf(a.x); lo.y = f2bf(a.y); lo.z = f2bf(a.z); lo.w = f2bf(a.w);
    hi.x = f2bf(b.x); hi.y = f2bf(b.y); hi.z = f2bf(b.z); hi.w = f2bf(b.w);
    *(ushort4*)(dst + i)     = lo;
    *(ushort4*)(dst + i + 4) = hi;
}

// ---------------------------------------------------------------------------
// bf16 MFMA projection GEMM (m97 structure + swizzled LDS):
// C[i,j] = sum_k A[i,k]*B[j,k]; 128x128 tile, BK=64, 4 waves, 4x4 frags.
// z=0: A=x, B=Wq -> q bf16 [B,H,S,D] scaled 1/8
// z=1: A=x, B=Wk -> k bf16 [B,H,S,D]
// z=2: A=Wv, B=x (swapped) -> v bf16 [B,H,D,S] with coalesced stores
// ---------------------------------------------------------------------------
__global__ __launch_bounds__(256, 3) void gemm_kernel(
    const unsigned short* __restrict__ xb,
    const unsigned short* __restrict__ wqb, const unsigned short* __restrict__ wkb,
    const unsigned short* __restrict__ wvb,
    const float* __restrict__ bq, const float* __restrict__ bk,
    const float* __restrict__ bv,
    unsigned short* __restrict__ qb, unsigned short* __restrict__ kb,
    unsigned short* __restrict__ vb)
{
    constexpr int BM = 128, BK = 64;
    __shared__ unsigned short As[BM * BK];   // 16 KB, swizzled rows of 64 shorts
    __shared__ unsigned short Bs[BM * BK];   // 16 KB

    const int t    = threadIdx.x;
    const int lane = t & 63;
    const int w    = t >> 6;
    const int l15  = lane & 15;
    const int quad = lane >> 4;
    const int wm   = w & 1;
    const int wn   = w >> 1;
    const int m0   = blockIdx.x * BM;
    const int n0   = blockIdx.y * BM;
    const int z    = blockIdx.z;

    const unsigned short *Ab, *Bb; const float* bias; unsigned short* outp;
    int i0, j0; float sc = 1.0f;
    if (z == 0)      { Ab = xb;  Bb = wqb; bias = bq; outp = qb; i0 = m0; j0 = n0; sc = 0.125f; }
    else if (z == 1) { Ab = xb;  Bb = wkb; bias = bk; outp = kb; i0 = m0; j0 = n0; }
    else             { Ab = wvb; Bb = xb;  bias = bv; outp = vb; i0 = n0; j0 = m0; }

    const int lrow = lane >> 3;                         // 0..7
    const int gch  = ((lane & 7) ^ (lrow & 7)) * 8;     // swizzle-inverse global chunk
    const int lsl  = (lane & 7) * 8;                    // physical LDS slot (shorts)

    f32x4 acc[4][4];
    #pragma unroll
    for (int mt = 0; mt < 4; ++mt)
        #pragma unroll
        for (int nt = 0; nt < 4; ++nt)
            #pragma unroll
            for (int r = 0; r < 4; ++r) acc[mt][nt][r] = 0.f;

    for (int k0 = 0; k0 < E_; k0 += BK) {
        __syncthreads();
        #pragma unroll
        for (int is = 0; is < 4; ++is) {
            int r = (w * 4 + is) * 8 + lrow;
            gload16(Ab + (size_t)(i0 + r) * E_ + k0 + gch, &As[r * BK + lsl]);
            gload16(Bb + (size_t)(j0 + r) * E_ + k0 + gch, &Bs[r * BK + lsl]);
        }
        __syncthreads();

        #pragma unroll
        for (int ks = 0; ks < 2; ++ks) {
            bf16x8 af[4], bfr[4];
            #pragma unroll
            for (int mt = 0; mt < 4; ++mt)
                af[mt] = *(const bf16x8*)&As[SWZ(wm*64 + mt*16 + l15, ks*4 + quad)];
            #pragma unroll
            for (int nt = 0; nt < 4; ++nt)
                bfr[nt] = *(const bf16x8*)&Bs[SWZ(wn*64 + nt*16 + l15, ks*4 + quad)];
            #pragma unroll
            for (int mt = 0; mt < 4; ++mt)
                #pragma unroll
                for (int nt = 0; nt < 4; ++nt)
                    acc[mt][nt] = __builtin_amdgcn_mfma_f32_16x16x32_bf16(
                        af[mt], bfr[nt], acc[mt][nt], 0, 0, 0);
        }
    }

    if (z < 2) {
        float bj[4];
        #pragma unroll
        for (int nt = 0; nt < 4; ++nt) bj[nt] = bias[j0 + wn*64 + nt*16 + l15];
        #pragma unroll
        for (int mt = 0; mt < 4; ++mt) {
            #pragma unroll
            for (int r = 0; r < 4; ++r) {
                int i = i0 + wm*64 + mt*16 + quad*4 + r;   // m index (b,s)
                int b = i >> 11, s = i & (S_ - 1);
                #pragma unroll
                for (int nt = 0; nt < 4; ++nt) {
                    int j = j0 + wn*64 + nt*16 + l15;      // n index (h,d)
                    int h = j >> 6, d = j & 63;
                    outp[(((size_t)(b * H_ + h) * S_) + s) * D_ + d] =
                        f2bf((acc[mt][nt][r] + bj[nt]) * sc);
                }
            }
        }
    } else {
        #pragma unroll
        for (int mt = 0; mt < 4; ++mt) {
            #pragma unroll
            for (int r = 0; r < 4; ++r) {
                int i = i0 + wm*64 + mt*16 + quad*4 + r;   // n index (h,d)
                int h = i >> 6, d = i & 63;
                float bi = bias[i];
                #pragma unroll
                for (int nt = 0; nt < 4; ++nt) {
                    int j = j0 + wn*64 + nt*16 + l15;      // m index (b,s)
                    int b = j >> 11, s = j & (S_ - 1);
                    outp[(((size_t)(b * H_ + h) * D_) + d) * S_ + s] =
                        f2bf(acc[mt][nt][r] + bi);
                }
            }
        }
    }
}

// ---------------------------------------------------------------------------
// MFMA attention. Block = 512 threads = 8 waves; 128 queries/block, 16/wave.
// K-tiles of 64. gload16 staging into XOR-swizzled Ks/Vt; P written as bf16
// into a wave-private LDS region (no barrier between softmax and PV); window
// mask hoisted to a wave-uniform per-16x16-tile branch (band tiles only).
// Denominator accumulated from the SAME truncated p values so the bf16
// truncation bias cancels exactly under normalization.
// ---------------------------------------------------------------------------
__global__ __launch_bounds__(512, 4) void attn_kernel(
    const unsigned short* __restrict__ Q, const unsigned short* __restrict__ K,
    const unsigned short* __restrict__ V, float* __restrict__ out)
{
    constexpr int TQ = 128, TK = 64, PSTR = 72;
    __shared__ unsigned short Ks[TK * 64];    // 8 KB, swizzled [key][d]
    __shared__ unsigned short Vt[D_ * 64];    // 8 KB, swizzled [d][key]
    __shared__ unsigned short Pq[TQ * PSTR];  // 18 KB, [q_loc][key] bf16, wave-private rows

    const int t    = threadIdx.x;
    const int lane = t & 63;
    const int w    = t >> 6;        // wave 0..7
    const int l15  = lane & 15;
    const int quad = lane >> 4;
    const int bh   = blockIdx.y;
    const int q0   = blockIdx.x * TQ;
    const int wq0  = q0 + w * 16;   // this wave's query base

    const unsigned short* Qp = Q + (size_t)bh * S_ * D_;
    const unsigned short* Kp = K + (size_t)bh * S_ * D_;
    const unsigned short* Vp = V + (size_t)bh * D_ * S_;   // [d][s]

    // Q A-frags held in regs for the whole kernel
    bf16x8 qf[2];
    #pragma unroll
    for (int ks = 0; ks < 2; ++ks)
        qf[ks] = *(const bf16x8*)(Qp + (size_t)(wq0 + l15) * D_ + ks*32 + quad*8);

    f32x4 Oacc[4];
    #pragma unroll
    for (int nt = 0; nt < 4; ++nt)
        #pragma unroll
        for (int r = 0; r < 4; ++r) Oacc[nt][r] = 0.f;
    float dsum[4] = {};

    // staging addresses (swizzle-inverse on the global side)
    const int lrow = lane >> 3;                       // 0..7
    const int gch  = ((lane & 7) ^ (lrow & 7)) * 8;   // shorts
    const int srow = w * 8 + lrow;                    // 0..63 (key row / d row)
    const unsigned short* kgp = Kp + (size_t)srow * D_ + gch;
    const unsigned short* vgp = Vp + (size_t)srow * S_ + gch;

    for (int k0 = 0; k0 < S_; k0 += TK) {
        __syncthreads();                 // prior iter done reading Ks/Vt
        gload16(kgp, &Ks[t * 8]);
        gload16(vgp, &Vt[t * 8]);
        kgp += TK * D_;
        vgp += TK;
        __syncthreads();                 // staged (compiler drains vmcnt)

        // ---- S = Q K^T : 16 q x 64 keys per wave ----
        f32x4 sacc[4];
        #pragma unroll
        for (int nt = 0; nt < 4; ++nt)
            #pragma unroll
            for (int r = 0; r < 4; ++r) sacc[nt][r] = 0.f;
        #pragma unroll
        for (int nt = 0; nt < 4; ++nt) {
            bf16x8 kf0 = *(const bf16x8*)&Ks[SWZ(nt*16 + l15, quad)];
            bf16x8 kf1 = *(const bf16x8*)&Ks[SWZ(nt*16 + l15, 4 + quad)];
            sacc[nt] = __builtin_amdgcn_mfma_f32_16x16x32_bf16(qf[0], kf0, sacc[nt], 0, 0, 0);
            sacc[nt] = __builtin_amdgcn_mfma_f32_16x16x32_bf16(qf[1], kf1, sacc[nt], 0, 0, 0);
        }

        // ---- softmax numerator: exp + (rare) inverted-window mask ----
        #pragma unroll
        for (int nt = 0; nt < 4; ++nt) {
            const int kt0 = k0 + nt*16;
            const bool band = (unsigned)(wq0 - kt0 + 18) <= 36u;  // wave-uniform
            #pragma unroll
            for (int r = 0; r < 4; ++r) {
                float p;
                if (band) {
                    int dlt = (wq0 + quad*4 + r) - (kt0 + l15);
                    if (dlt < 0) dlt = -dlt;
                    p = (dlt <= WIN_) ? 0.f : __expf(sacc[nt][r]);
                } else {
                    p = __expf(sacc[nt][r]);
                }
                union { float f; unsigned int u; } c; c.f = p;
                c.u &= 0xFFFF0000u;                  // bf16-representable (truncate)
                dsum[r] += c.f;
                Pq[(w*16 + quad*4 + r) * PSTR + nt*16 + l15] =
                    (unsigned short)(c.u >> 16);
            }
        }
        // no barrier: P rows are wave-private; compiler orders via lgkmcnt

        // ---- O += P V ----
        #pragma unroll
        for (int ks = 0; ks < 2; ++ks) {
            bf16x8 pf = *(const bf16x8*)&Pq[(w*16 + l15) * PSTR + ks*32 + quad*8];
            #pragma unroll
            for (int nt = 0; nt < 4; ++nt) {
                bf16x8 vf = *(const bf16x8*)&Vt[SWZ(nt*16 + l15, ks*4 + quad)];
                Oacc[nt] = __builtin_amdgcn_mfma_f32_16x16x32_bf16(pf, vf, Oacc[nt], 0, 0, 0);
            }
        }
    }

    // ---- normalize + store: out [B,S,H,D] fp32 ----
    const int b  = bh >> 4;
    const int hh = bh & 15;
    #pragma unroll
    for (int r = 0; r < 4; ++r) {
        float d = dsum[r];
        d += __shfl_xor(d, 1);
        d += __shfl_xor(d, 2);
        d += __shfl_xor(d, 4);
        d += __shfl_xor(d, 8);
        const float iv = 1.f / d;
        const int qg = wq0 + quad*4 + r;
        float* op = out + (((size_t)b * S_ + qg) * H_ + hh) * D_;
        #pragma unroll
        for (int nt = 0; nt < 4; ++nt)
            op[nt*16 + l15] = Oacc[nt][r] * iv;
    }
}

extern "C" void kernel_launch(void* const* d_in, const int* in_sizes, int n_in,
                              void* d_out, int out_size, void* d_ws, size_t ws_size,
                              hipStream_t stream) {
    const float* x  = (const float*)d_in[0];
    const float* Wq = (const float*)d_in[1];
    const float* bq = (const float*)d_in[2];
    const float* Wk = (const float*)d_in[3];
    const float* bk = (const float*)d_in[4];
    const float* Wv = (const float*)d_in[5];
    const float* bv = (const float*)d_in[6];
    float* out = (float*)d_out;

    const size_t per = (size_t)B_ * H_ * S_ * D_;   // 4,194,304 elements
    const size_t wsz = (size_t)E_ * E_;             // 1,048,576
    unsigned short* qb  = (unsigned short*)d_ws;
    unsigned short* kb  = qb + per;
    unsigned short* vb  = kb + per;
    unsigned short* xbf = vb + per;
    unsigned short* wqb = xbf + per;
    unsigned short* wkb = wqb + wsz;
    unsigned short* wvb = wkb + wsz;

    dim3 cgrid((B_ * S_ * E_ + 2047) / 2048, 4);
    cast_kernel<<<cgrid, 256, 0, stream>>>(x, Wq, Wk, Wv, xbf, wqb, wkb, wvb);

    dim3 ggrid(B_ * S_ / 128, E_ / 128, 3);
    gemm_kernel<<<ggrid, 256, 0, stream>>>(xbf, wqb, wkb, wvb, bq, bk, bv, qb, kb, vb);

    dim3 agrid(S_ / 128, B_ * H_);
    attn_kernel<<<agrid, 512, 0, stream>>>(qb, kb, vb, out);
}